// Round 5
// baseline (124.846 us; speedup 1.0000x reference)
//
#include <hip/hip_runtime.h>
#include <hip/hip_bf16.h>
#include <stdint.h>

typedef __attribute__((ext_vector_type(8)))  short    short8;
typedef __attribute__((ext_vector_type(4)))  float    floatx4;
typedef __attribute__((ext_vector_type(16))) float    floatx16;
typedef __attribute__((ext_vector_type(2)))  uint32_t uintx2;

// HW packed fp32->bf16 (RTNE), low half = first operand.
static __device__ __forceinline__ uint32_t cvtpk(float lo, float hi) {
  uint32_t r;
  asm("v_cvt_pk_bf16_f32 %0, %1, %2" : "=v"(r) : "v"(lo), "v"(hi));
  return r;
}

static __device__ __forceinline__ short8 pack8c(floatx4 a, floatx4 b) {
  union { uint32_t u[4]; short8 s; } r;
  r.u[0] = cvtpk(a[0], a[1]); r.u[1] = cvtpk(a[2], a[3]);
  r.u[2] = cvtpk(b[0], b[1]); r.u[3] = cvtpk(b[2], b[3]);
  return r.s;
}

#define MFMA32(a, b, c) __builtin_amdgcn_mfma_f32_32x32x16_bf16((a), (b), (c), 0, 0, 0)

constexpr int S_LEN = 2048;
constexpr int DH    = 64;
constexpr int QBLK  = 128;   // 4 waves x 32 q-rows
constexpr int KVBLK = 64;
constexpr int NT    = S_LEN / KVBLK;

// permlane32_swap: new_a = [a.lo32, b.lo32] ; new_b = [a.hi32, b.hi32]
static __device__ __forceinline__ void swap32(uint32_t& a, uint32_t& b, int hi) {
#if __has_builtin(__builtin_amdgcn_permlane32_swap)
  typedef int intx2 __attribute__((ext_vector_type(2)));
  intx2 r = __builtin_amdgcn_permlane32_swap((int)a, (int)b, false, false);
  a = (uint32_t)r[0]; b = (uint32_t)r[1];
#else
  uint32_t pa = (uint32_t)__shfl_xor((int)a, 32, 64);
  uint32_t pb = (uint32_t)__shfl_xor((int)b, 32, 64);
  uint32_t na = hi ? pb : a;
  uint32_t nb = hi ? b  : pa;
  a = na; b = nb;
#endif
}

__global__ __launch_bounds__(256, 2)
void attn_fwd(const float* __restrict__ Q, const float* __restrict__ V,
              const float* __restrict__ K, const float* __restrict__ AM,
              const float* __restrict__ SM, float* __restrict__ O)
{
  __shared__ ushort Kl[2][KVBLK * DH];   // [kv][d]  bf16, chunk^=(row&7) swizzle
  __shared__ ushort Vt[2][DH * KVBLK];   // [d][kv]  bf16 (plain V), swizzled
  __shared__ float  smlds[S_LEN];        // seq_mask row for this b (fp32)

  const int bh   = blockIdx.x;
  const int qt   = blockIdx.y;
  const int tid  = threadIdx.x;
  const int lane = tid & 63;
  const int wave = tid >> 6;
  const int l31  = lane & 31;
  const int hi   = lane >> 5;

  const float* qptr  = Q  + (size_t)bh * S_LEN * DH;
  const float* kptr  = K  + (size_t)bh * S_LEN * DH;
  const float* vptr  = V  + (size_t)bh * S_LEN * DH;
  const float* amptr = AM + (size_t)(bh >> 4) * S_LEN * S_LEN;
  const float* smptr = SM + (size_t)(bh >> 4) * S_LEN;
  float* optr = O + (size_t)bh * S_LEN * DH;

  // stage seq_mask once (fp32)
  for (int i = tid; i < S_LEN / 4; i += 256)
    ((floatx4*)smlds)[i] = ((const floatx4*)smptr)[i];

  const int qw = qt * QBLK + wave * 32;  // this wave's q base

  // ---- Q fragments: lane holds Q[qw + (l&31)][s*16 + hi*8 + 0..7] ----
  short8 qf[4];
  {
    const float* p = qptr + (size_t)(qw + l31) * DH + hi * 8;
    #pragma unroll
    for (int s = 0; s < 4; ++s) {
      floatx4 f0 = *(const floatx4*)(p + s * 16);
      floatx4 f1 = *(const floatx4*)(p + s * 16 + 4);
      qf[s] = pack8c(f0, f1);
    }
  }

  // staging indices
  const int krow = tid >> 2;          // K: one kv row, 16 d
  const int kcol = (tid & 3) * 16;
  const int kcb  = (tid & 3) * 2;
  const int vr0  = (tid & 15) * 4;    // V: 4 kv rows, 4 d
  const int vd0  = (tid >> 4) * 4;

  floatx4 kreg[4], vreg[4];
  floatx4 amA[2][4], amB[2][4];

  auto LOADKV = [&](int t) {
    const float* kg = kptr + (size_t)(t * KVBLK + krow) * DH + kcol;
    #pragma unroll
    for (int j = 0; j < 4; ++j) kreg[j] = ((const floatx4*)kg)[j];
    #pragma unroll
    for (int i = 0; i < 4; ++i)
      vreg[i] = *(const floatx4*)(vptr + (size_t)(t * KVBLK + vr0 + i) * DH + vd0);
  };

  auto WRITEKV = [&](int c) {
    // K tile [kv][d]
    const int sw = krow & 7;
    *(short8*)&Kl[c][krow * 64 + ((kcb ^ sw) * 8)]       = pack8c(kreg[0], kreg[1]);
    *(short8*)&Kl[c][krow * 64 + (((kcb + 1) ^ sw) * 8)] = pack8c(kreg[2], kreg[3]);
    // V^T tile [d][kv] (plain bf16(V))
    #pragma unroll
    for (int d = 0; d < 4; ++d) {
      uintx2 w;
      w[0] = cvtpk(vreg[0][d], vreg[1][d]);
      w[1] = cvtpk(vreg[2][d], vreg[3][d]);
      const int row = vd0 + d;
      const int ch  = (vr0 >> 3) ^ (row & 7);
      *(uintx2*)&Vt[c][row * 64 + ch * 8 + (vr0 & 7)] = w;
    }
  };

  auto LOADAM = [&](int t, floatx4 (&am)[2][4]) {
    const float* base = amptr + (size_t)(qw + l31) * S_LEN + t * KVBLK + hi * 4;
    #pragma unroll
    for (int blk = 0; blk < 2; ++blk)
      #pragma unroll
      for (int j = 0; j < 4; ++j)
        am[blk][j] = *(const floatx4*)(base + blk * 32 + j * 8);
  };

  // prologue
  LOADKV(0);
  WRITEKV(0);
  LOADAM(0, amA);

  float m_run = -3.0e38f, l_run = 0.f;
  floatx16 oacc[2];
  #pragma unroll
  for (int db = 0; db < 2; ++db)
    #pragma unroll
    for (int r = 0; r < 16; ++r) oacc[db][r] = 0.f;

  // one K/V-tile step; c = LDS buffer of tile t (compile-time at call site)
  auto STEP = [&](int t, int c, floatx4 (&amC)[2][4], floatx4 (&amN)[2][4]) {
    __syncthreads();

    // ---- QK^T: sacc[blk] = S^T[kv][q]; lane q=l31, kv = blk*32+crow(r,hi) ----
    floatx16 sacc[2];
    __builtin_amdgcn_s_setprio(1);
    #pragma unroll
    for (int blk = 0; blk < 2; ++blk) {
      #pragma unroll
      for (int r = 0; r < 16; ++r) sacc[blk][r] = 0.f;
      const int row = blk * 32 + l31;
      const int sw  = row & 7;
      #pragma unroll
      for (int s = 0; s < 4; ++s) {
        const int ch = (s * 2 + hi) ^ sw;
        short8 kf = *(const short8*)&Kl[c][row * 64 + ch * 8];
        sacc[blk] = MFMA32(kf, qf[s], sacc[blk]);
      }
    }
    __builtin_amdgcn_s_setprio(0);

    // ---- scores (e-domain, r4 numerics); lane-local row max ----
    float p[2][16];
    float pmax = -3.0e38f;
    #pragma unroll
    for (int blk = 0; blk < 2; ++blk)
      #pragma unroll
      for (int r = 0; r < 16; ++r) {
        const float v = fmaf(sacc[blk][r], 0.125f, amC[blk][r >> 2][r & 3]);
        p[blk][r] = v;
        pmax = fmaxf(pmax, v);
      }
    pmax = fmaxf(pmax, __shfl_xor(pmax, 32, 64));

    // ---- online rescale (skip is bit-exact when no row grew: fac==1.0) ----
    if (__any(pmax > m_run)) {
      const float mnew = fmaxf(m_run, pmax);
      const float fac  = __expf(m_run - mnew);
      float fw[16];
      #pragma unroll
      for (int r = 0; r < 16; ++r)
        fw[r] = __shfl(fac, (r & 3) + 8 * (r >> 2) + 4 * hi, 64);
      #pragma unroll
      for (int db = 0; db < 2; ++db)
        #pragma unroll
        for (int r = 0; r < 16; ++r) oacc[db][r] *= fw[r];
      l_run *= fac;
      m_run = mnew;
    }

    // ---- P = exp(s - m) in fp32; denominator from UNROUNDED fp32 P ----
    float ssum = 0.f;
    #pragma unroll
    for (int blk = 0; blk < 2; ++blk)
      #pragma unroll
      for (int r = 0; r < 16; ++r) {
        const float e = __expf(p[blk][r] - m_run);
        p[blk][r] = e;
        ssum += e;
      }
    ssum += __shfl_xor(ssum, 32, 64);
    l_run += ssum;

    // ---- prefetch next tile (clamped; last step re-reads tile NT-1) ----
    const int tn = (t + 1 < NT) ? t + 1 : NT - 1;
    LOADKV(tn);
    LOADAM(tn, amN);

    // ---- seq_mask in fragment layout (broadcast LDS reads) ----
    floatx4 smv[2][4];
    #pragma unroll
    for (int blk = 0; blk < 2; ++blk)
      #pragma unroll
      for (int j = 0; j < 4; ++j)
        smv[blk][j] = *(const floatx4*)&smlds[t * KVBLK + blk * 32 + hi * 4 + j * 8];

    // ---- (P * sm) in fp32 -> bf16 A-fragments (cvt_pk + permlane32_swap) ----
    uint32_t pw[2][2][4];
    #pragma unroll
    for (int blk = 0; blk < 2; ++blk)
      #pragma unroll
      for (int ks = 0; ks < 2; ++ks) {
        uint32_t w0 = cvtpk(p[blk][ks * 8 + 0] * smv[blk][ks * 2 + 0][0],
                            p[blk][ks * 8 + 1] * smv[blk][ks * 2 + 0][1]);
        uint32_t w1 = cvtpk(p[blk][ks * 8 + 2] * smv[blk][ks * 2 + 0][2],
                            p[blk][ks * 8 + 3] * smv[blk][ks * 2 + 0][3]);
        uint32_t w2 = cvtpk(p[blk][ks * 8 + 4] * smv[blk][ks * 2 + 1][0],
                            p[blk][ks * 8 + 5] * smv[blk][ks * 2 + 1][1]);
        uint32_t w3 = cvtpk(p[blk][ks * 8 + 6] * smv[blk][ks * 2 + 1][2],
                            p[blk][ks * 8 + 7] * smv[blk][ks * 2 + 1][3]);
        swap32(w0, w2, hi);
        swap32(w1, w3, hi);
        pw[blk][ks][0] = w0; pw[blk][ks][1] = w1;
        pw[blk][ks][2] = w2; pw[blk][ks][3] = w3;
      }

    // ---- PV: oacc[db] += (P.sm)(32q x 64kv) . V(64kv x 64d) ----
    __builtin_amdgcn_s_setprio(1);
    #pragma unroll
    for (int blk = 0; blk < 2; ++blk)
      #pragma unroll
      for (int ks = 0; ks < 2; ++ks) {
        union { uint32_t u[4]; short8 s; } af;
        af.u[0] = pw[blk][ks][0]; af.u[1] = pw[blk][ks][1];
        af.u[2] = pw[blk][ks][2]; af.u[3] = pw[blk][ks][3];
        #pragma unroll
        for (int db = 0; db < 2; ++db) {
          const int row = db * 32 + l31;
          const int ch  = (blk * 4 + ks * 2 + hi) ^ (row & 7);
          short8 vf = *(const short8*)&Vt[c][row * 64 + ch * 8];
          oacc[db] = MFMA32(af.s, vf, oacc[db]);
        }
      }
    __builtin_amdgcn_s_setprio(0);

    // ---- write staged t+1 into the other buffer ----
    WRITEKV(c ^ 1);
  };

  #pragma unroll 1
  for (int t = 0; t < NT; t += 2) {
    STEP(t,     0, amA, amB);
    STEP(t + 1, 1, amB, amA);
  }

  // ---- epilogue: out = oacc / l ----
  const float inv = 1.0f / l_run;
  float iw[16];
  #pragma unroll
  for (int r = 0; r < 16; ++r)
    iw[r] = __shfl(inv, (r & 3) + 8 * (r >> 2) + 4 * hi, 64);
  #pragma unroll
  for (int db = 0; db < 2; ++db)
    #pragma unroll
    for (int r = 0; r < 16; ++r) {
      const int qr = (r & 3) + 8 * (r >> 2) + 4 * hi;
      optr[(size_t)(qw + qr) * DH + db * 32 + l31] = oacc[db][r] * iw[r];
    }
}

extern "C" void kernel_launch(void* const* d_in, const int* in_sizes, int n_in,
                              void* d_out, int out_size, void* d_ws, size_t ws_size,
                              hipStream_t stream) {
  const float* q  = (const float*)d_in[0];
  const float* v  = (const float*)d_in[1];
  const float* k  = (const float*)d_in[2];
  const float* am = (const float*)d_in[3];
  const float* sm = (const float*)d_in[4];
  float* o = (float*)d_out;

  dim3 grid(32, S_LEN / QBLK);  // (b*h, q-tile of 128)
  attn_fwd<<<grid, 256, 0, stream>>>(q, v, k, am, sm, o);
}

// Round 6
// 121.313 us; speedup vs baseline: 1.0291x; 1.0291x over previous
//
#include <hip/hip_runtime.h>
#include <hip/hip_bf16.h>
#include <stdint.h>

typedef __attribute__((ext_vector_type(8)))  short    short8;
typedef __attribute__((ext_vector_type(4)))  float    floatx4;
typedef __attribute__((ext_vector_type(16))) float    floatx16;
typedef __attribute__((ext_vector_type(2)))  uint32_t uintx2;

// HW packed fp32->bf16 (RTNE), low half = first operand.
static __device__ __forceinline__ uint32_t cvtpk(float lo, float hi) {
  uint32_t r;
  asm("v_cvt_pk_bf16_f32 %0, %1, %2" : "=v"(r) : "v"(lo), "v"(hi));
  return r;
}

static __device__ __forceinline__ short8 pack8c(floatx4 a, floatx4 b) {
  union { uint32_t u[4]; short8 s; } r;
  r.u[0] = cvtpk(a[0], a[1]); r.u[1] = cvtpk(a[2], a[3]);
  r.u[2] = cvtpk(b[0], b[1]); r.u[3] = cvtpk(b[2], b[3]);
  return r.s;
}

#define MFMA32(a, b, c) __builtin_amdgcn_mfma_f32_32x32x16_bf16((a), (b), (c), 0, 0, 0)

// end-of-tile barrier: retire LDS ops (this wave's ds_reads AND ds_writes),
// then s_barrier. Global (vmcnt) loads stay in flight across it (T4).
#define TILE_BARRIER() asm volatile("s_waitcnt lgkmcnt(0)\n\ts_barrier" ::: "memory")

constexpr int S_LEN = 2048;
constexpr int DH    = 64;
constexpr int QBLK  = 128;   // 4 waves x 32 q-rows
constexpr int KVBLK = 64;
constexpr int NT    = S_LEN / KVBLK;

// permlane32_swap: new_a = [a.lo32, b.lo32] ; new_b = [a.hi32, b.hi32]
static __device__ __forceinline__ void swap32(uint32_t& a, uint32_t& b, int hi) {
#if __has_builtin(__builtin_amdgcn_permlane32_swap)
  typedef int intx2 __attribute__((ext_vector_type(2)));
  intx2 r = __builtin_amdgcn_permlane32_swap((int)a, (int)b, false, false);
  a = (uint32_t)r[0]; b = (uint32_t)r[1];
#else
  uint32_t pa = (uint32_t)__shfl_xor((int)a, 32, 64);
  uint32_t pb = (uint32_t)__shfl_xor((int)b, 32, 64);
  uint32_t na = hi ? pb : a;
  uint32_t nb = hi ? b  : pa;
  a = na; b = nb;
#endif
}

__global__ __launch_bounds__(256, 2)
void attn_fwd(const float* __restrict__ Q, const float* __restrict__ V,
              const float* __restrict__ K, const float* __restrict__ AM,
              const float* __restrict__ SM, float* __restrict__ O)
{
  __shared__ ushort Kl[2][KVBLK * DH];   // [kv][d]  bf16, chunk^=(row&7) swizzle
  __shared__ ushort Vt[2][DH * KVBLK];   // [d][kv]  bf16 (plain V), swizzled
  __shared__ float  smlds[S_LEN];        // seq_mask row for this b (fp32)

  const int bh   = blockIdx.x;
  const int qt   = blockIdx.y;
  const int tid  = threadIdx.x;
  const int lane = tid & 63;
  const int wave = tid >> 6;
  const int l31  = lane & 31;
  const int hi   = lane >> 5;

  const float* qptr  = Q  + (size_t)bh * S_LEN * DH;
  const float* kptr  = K  + (size_t)bh * S_LEN * DH;
  const float* vptr  = V  + (size_t)bh * S_LEN * DH;
  const float* amptr = AM + (size_t)(bh >> 4) * S_LEN * S_LEN;
  const float* smptr = SM + (size_t)(bh >> 4) * S_LEN;
  float* optr = O + (size_t)bh * S_LEN * DH;

  // stage seq_mask once (fp32)
  for (int i = tid; i < S_LEN / 4; i += 256)
    ((floatx4*)smlds)[i] = ((const floatx4*)smptr)[i];

  const int qw = qt * QBLK + wave * 32;  // this wave's q base

  // ---- Q fragments: lane holds Q[qw + (l&31)][s*16 + hi*8 + 0..7] ----
  short8 qf[4];
  {
    const float* p = qptr + (size_t)(qw + l31) * DH + hi * 8;
    #pragma unroll
    for (int s = 0; s < 4; ++s) {
      floatx4 f0 = *(const floatx4*)(p + s * 16);
      floatx4 f1 = *(const floatx4*)(p + s * 16 + 4);
      qf[s] = pack8c(f0, f1);
    }
  }

  // staging indices
  const int krow = tid >> 2;          // K: one kv row, 16 d
  const int kcol = (tid & 3) * 16;
  const int kcb  = (tid & 3) * 2;
  const int vr0  = (tid & 15) * 4;    // V: 4 kv rows, 4 d
  const int vd0  = (tid >> 4) * 4;

  floatx4 kreg[4], vreg[4];
  floatx4 amA[2][4], amB[2][4];

  auto LOADKV = [&](int t) {
    const float* kg = kptr + (size_t)(t * KVBLK + krow) * DH + kcol;
    #pragma unroll
    for (int j = 0; j < 4; ++j) kreg[j] = ((const floatx4*)kg)[j];
    #pragma unroll
    for (int i = 0; i < 4; ++i)
      vreg[i] = *(const floatx4*)(vptr + (size_t)(t * KVBLK + vr0 + i) * DH + vd0);
  };

  auto WRITEKV = [&](int c) {
    // K tile [kv][d]
    const int sw = krow & 7;
    *(short8*)&Kl[c][krow * 64 + ((kcb ^ sw) * 8)]       = pack8c(kreg[0], kreg[1]);
    *(short8*)&Kl[c][krow * 64 + (((kcb + 1) ^ sw) * 8)] = pack8c(kreg[2], kreg[3]);
    // V^T tile [d][kv] (plain bf16(V))
    #pragma unroll
    for (int d = 0; d < 4; ++d) {
      uintx2 w;
      w[0] = cvtpk(vreg[0][d], vreg[1][d]);
      w[1] = cvtpk(vreg[2][d], vreg[3][d]);
      const int row = vd0 + d;
      const int ch  = (vr0 >> 3) ^ (row & 7);
      *(uintx2*)&Vt[c][row * 64 + ch * 8 + (vr0 & 7)] = w;
    }
  };

  auto LOADAM = [&](int t, floatx4 (&am)[2][4]) {
    const float* base = amptr + (size_t)(qw + l31) * S_LEN + t * KVBLK + hi * 4;
    #pragma unroll
    for (int blk = 0; blk < 2; ++blk)
      #pragma unroll
      for (int j = 0; j < 4; ++j)
        am[blk][j] = *(const floatx4*)(base + blk * 32 + j * 8);
  };

  // prologue: stage tile 0, then one full barrier
  LOADKV(0);
  WRITEKV(0);
  LOADAM(0, amA);
  TILE_BARRIER();

  float m_run = -3.0e38f, l_run = 0.f;
  floatx16 oacc[2];
  #pragma unroll
  for (int db = 0; db < 2; ++db)
    #pragma unroll
    for (int r = 0; r < 16; ++r) oacc[db][r] = 0.f;

  // one K/V-tile step; c = LDS buffer of tile t (compile-time at call site)
  auto STEP = [&](int t, int c, floatx4 (&amC)[2][4], floatx4 (&amN)[2][4]) {
    // ---- QK^T: sacc[blk] = S^T[kv][q]; lane q=l31, kv = blk*32+crow(r,hi) ----
    floatx16 sacc[2];
    __builtin_amdgcn_s_setprio(1);
    #pragma unroll
    for (int blk = 0; blk < 2; ++blk) {
      #pragma unroll
      for (int r = 0; r < 16; ++r) sacc[blk][r] = 0.f;
      const int row = blk * 32 + l31;
      const int sw  = row & 7;
      #pragma unroll
      for (int s = 0; s < 4; ++s) {
        const int ch = (s * 2 + hi) ^ sw;
        short8 kf = *(const short8*)&Kl[c][row * 64 + ch * 8];
        sacc[blk] = MFMA32(kf, qf[s], sacc[blk]);
      }
    }
    __builtin_amdgcn_s_setprio(0);

    // ---- issue next tile's loads NOW (max cover before consumption) ----
    const int tn = (t + 1 < NT) ? t + 1 : NT - 1;
    LOADKV(tn);
    LOADAM(tn, amN);

    // ---- scores (e-domain, r4 numerics); lane-local row max ----
    float p[2][16];
    float pmax = -3.0e38f;
    #pragma unroll
    for (int blk = 0; blk < 2; ++blk)
      #pragma unroll
      for (int r = 0; r < 16; ++r) {
        const float v = fmaf(sacc[blk][r], 0.125f, amC[blk][r >> 2][r & 3]);
        p[blk][r] = v;
        pmax = fmaxf(pmax, v);
      }
    pmax = fmaxf(pmax, __shfl_xor(pmax, 32, 64));

    // ---- online rescale (skip is bit-exact when no row grew: fac==1.0) ----
    if (__any(pmax > m_run)) {
      const float mnew = fmaxf(m_run, pmax);
      const float fac  = __expf(m_run - mnew);
      float fw[16];
      #pragma unroll
      for (int r = 0; r < 16; ++r)
        fw[r] = __shfl(fac, (r & 3) + 8 * (r >> 2) + 4 * hi, 64);
      #pragma unroll
      for (int db = 0; db < 2; ++db)
        #pragma unroll
        for (int r = 0; r < 16; ++r) oacc[db][r] *= fw[r];
      l_run *= fac;
      m_run = mnew;
    }

    // ---- P = exp(s - m) in fp32; denominator from UNROUNDED fp32 P ----
    float ssum = 0.f;
    #pragma unroll
    for (int blk = 0; blk < 2; ++blk)
      #pragma unroll
      for (int r = 0; r < 16; ++r) {
        const float e = __expf(p[blk][r] - m_run);
        p[blk][r] = e;
        ssum += e;
      }
    ssum += __shfl_xor(ssum, 32, 64);
    l_run += ssum;

    // ---- seq_mask in fragment layout (broadcast LDS reads) ----
    floatx4 smv[2][4];
    #pragma unroll
    for (int blk = 0; blk < 2; ++blk)
      #pragma unroll
      for (int j = 0; j < 4; ++j)
        smv[blk][j] = *(const floatx4*)&smlds[t * KVBLK + blk * 32 + hi * 4 + j * 8];

    // ---- (P * sm) in fp32 -> bf16 A-fragments (cvt_pk + permlane32_swap) ----
    uint32_t pw[2][2][4];
    #pragma unroll
    for (int blk = 0; blk < 2; ++blk)
      #pragma unroll
      for (int ks = 0; ks < 2; ++ks) {
        uint32_t w0 = cvtpk(p[blk][ks * 8 + 0] * smv[blk][ks * 2 + 0][0],
                            p[blk][ks * 8 + 1] * smv[blk][ks * 2 + 0][1]);
        uint32_t w1 = cvtpk(p[blk][ks * 8 + 2] * smv[blk][ks * 2 + 0][2],
                            p[blk][ks * 8 + 3] * smv[blk][ks * 2 + 0][3]);
        uint32_t w2 = cvtpk(p[blk][ks * 8 + 4] * smv[blk][ks * 2 + 1][0],
                            p[blk][ks * 8 + 5] * smv[blk][ks * 2 + 1][1]);
        uint32_t w3 = cvtpk(p[blk][ks * 8 + 6] * smv[blk][ks * 2 + 1][2],
                            p[blk][ks * 8 + 7] * smv[blk][ks * 2 + 1][3]);
        swap32(w0, w2, hi);
        swap32(w1, w3, hi);
        pw[blk][ks][0] = w0; pw[blk][ks][1] = w1;
        pw[blk][ks][2] = w2; pw[blk][ks][3] = w3;
      }

    // ---- PV: oacc[db] += (P.sm)(32q x 64kv) . V(64kv x 64d) ----
    __builtin_amdgcn_s_setprio(1);
    #pragma unroll
    for (int blk = 0; blk < 2; ++blk)
      #pragma unroll
      for (int ks = 0; ks < 2; ++ks) {
        union { uint32_t u[4]; short8 s; } af;
        af.u[0] = pw[blk][ks][0]; af.u[1] = pw[blk][ks][1];
        af.u[2] = pw[blk][ks][2]; af.u[3] = pw[blk][ks][3];
        #pragma unroll
        for (int db = 0; db < 2; ++db) {
          const int row = db * 32 + l31;
          const int ch  = (blk * 4 + ks * 2 + hi) ^ (row & 7);
          short8 vf = *(const short8*)&Vt[c][row * 64 + ch * 8];
          oacc[db] = MFMA32(af.s, vf, oacc[db]);
        }
      }
    __builtin_amdgcn_s_setprio(0);

    // ---- write staged t+1 into the other buffer; single barrier per tile ----
    WRITEKV(c ^ 1);
    TILE_BARRIER();
  };

  #pragma unroll 1
  for (int t = 0; t < NT; t += 2) {
    STEP(t,     0, amA, amB);
    STEP(t + 1, 1, amB, amA);
  }

  // ---- epilogue: out = oacc / l ----
  const float inv = 1.0f / l_run;
  float iw[16];
  #pragma unroll
  for (int r = 0; r < 16; ++r)
    iw[r] = __shfl(inv, (r & 3) + 8 * (r >> 2) + 4 * hi, 64);
  #pragma unroll
  for (int db = 0; db < 2; ++db)
    #pragma unroll
    for (int r = 0; r < 16; ++r) {
      const int qr = (r & 3) + 8 * (r >> 2) + 4 * hi;
      optr[(size_t)(qw + qr) * DH + db * 32 + l31] = oacc[db][r] * iw[r];
    }
}

extern "C" void kernel_launch(void* const* d_in, const int* in_sizes, int n_in,
                              void* d_out, int out_size, void* d_ws, size_t ws_size,
                              hipStream_t stream) {
  const float* q  = (const float*)d_in[0];
  const float* v  = (const float*)d_in[1];
  const float* k  = (const float*)d_in[2];
  const float* am = (const float*)d_in[3];
  const float* sm = (const float*)d_in[4];
  float* o = (float*)d_out;

  dim3 grid(32, S_LEN / QBLK);  // (b*h, q-tile of 128)
  attn_fwd<<<grid, 256, 0, stream>>>(q, v, k, am, sm, o);
}